// Round 21
// baseline (190.354 us; speedup 1.0000x reference)
//
#include <hip/hip_runtime.h>
#include <math.h>

#define NB    16      // batch
#define CDIM  256
#define COUT  144     // 64 q + 16 k + 64 v
#define MPIX  4096    // 64*64
#define SCOPE 23
#define PADH  11
#define BNEPS 1e-5f

typedef __attribute__((ext_vector_type(4))) float f32x4;
typedef __attribute__((ext_vector_type(8))) short s16x8;

__device__ __forceinline__ unsigned short f2bf(float f) {
    unsigned u = __builtin_bit_cast(unsigned, f);
    unsigned r = (u + 0x7FFFu + ((u >> 16) & 1u)) >> 16;
    return (unsigned short)r;
}

// ---------------- K0: both weight-fragment preps merged ----------------
__global__ void prep_frags(const float* __restrict__ w, const float* __restrict__ wl,
                           short* __restrict__ wqf, short* __restrict__ wfrag) {
    int i = blockIdx.x * 256 + threadIdx.x;
    if (i < 36864) {
        int j = i & 7, lane = (i >> 3) & 63;
        int fi = i >> 9;
        int mf = fi % 9, kc = fi / 9;
        int o = mf * 16 + (lane & 15);
        int c = kc * 32 + (lane >> 4) * 8 + j;
        wqf[i] = (short)f2bf(w[o * 256 + c]);
        return;
    }
    int i2 = i - 36864;
    if (i2 < 23 * 64 * 8) {
        int j = i2 & 7, l = (i2 >> 3) & 63, dy = i2 >> 9;
        int k = l & 15, t = ((l >> 4) << 3) + j;
        float wv = (t < SCOPE) ? wl[k * 529 + dy * 23 + t] : 0.f;
        wfrag[i2] = (short)f2bf(wv);
    }
}

// ---------------- K1: qkv GEMM + fused BN stat partials + softmax denominator ----
__global__ void __launch_bounds__(256, 4) gemm_qkv(const float* __restrict__ x,
                                                   const short* __restrict__ wqf,
                                                   float* __restrict__ qkv,
                                                   float* __restrict__ statpart,
                                                   float* __restrict__ kpart) {
    __shared__ unsigned pk[16 * 65];
    __shared__ float ssum[4][144], ssq[4][144];
    __shared__ float sse[4][16];
    int mt = blockIdx.x, b = blockIdx.y;
    int m0 = mt * 64;
    int tid = threadIdx.x;
    int px64 = tid & 63, c2b = tid >> 6;
    int lane = tid & 63, wv = tid >> 6;
    int pxl = lane & 15, kgq = lane >> 4;
    const float* xb = x + (size_t)b * CDIM * MPIX;
    float* qtb = qkv + (size_t)b * COUT * MPIX;
    const s16x8* wfv = (const s16x8*)wqf;

    f32x4 acc[9];
#pragma unroll
    for (int mf = 0; mf < 9; mf++) acc[mf] = 0.f;

#pragma unroll 1
    for (int kc = 0; kc < 8; kc++) {
        if (kc > 0) __syncthreads();
#pragma unroll
        for (int it = 0; it < 4; it++) {
            int c2 = c2b + it * 4;
            float x0 = xb[(size_t)(kc * 32 + 2 * c2) * MPIX + m0 + px64];
            float x1 = xb[(size_t)(kc * 32 + 2 * c2 + 1) * MPIX + m0 + px64];
            pk[c2 * 65 + px64] = (unsigned)f2bf(x0) | ((unsigned)f2bf(x1) << 16);
        }
        __syncthreads();
        const unsigned* bp = &pk[kgq * 4 * 65 + wv * 16 + pxl];
        int4 bi = make_int4(bp[0], bp[65], bp[130], bp[195]);
        s16x8 bf = __builtin_bit_cast(s16x8, bi);
#pragma unroll
        for (int mf = 0; mf < 9; mf++) {
            s16x8 af = wfv[(kc * 9 + mf) * 64 + lane];
            acc[mf] = __builtin_amdgcn_mfma_f32_16x16x32_bf16(af, bf, acc[mf], 0, 0, 0);
        }
    }

    int m = m0 + wv * 16 + pxl;
#pragma unroll
    for (int mf = 0; mf < 9; mf++) {
#pragma unroll
        for (int r = 0; r < 4; r++) {
            int o = mf * 16 + kgq * 4 + r;
            if (mf < 4) qtb[(size_t)m * 64 + o] = acc[mf][r];
            else qkv[((size_t)b * COUT + o) * MPIX + m] = acc[mf][r];
        }
    }

#pragma unroll
    for (int mf = 0; mf < 9; mf++) {
#pragma unroll
        for (int r = 0; r < 4; r++) {
            float s = acc[mf][r];
            float s2 = s * s;
#pragma unroll
            for (int off = 1; off < 16; off <<= 1) {
                s += __shfl_xor(s, off);
                s2 += __shfl_xor(s2, off);
            }
            if (mf == 4) {
                float e = __expf(acc[mf][r]);
#pragma unroll
                for (int off = 1; off < 16; off <<= 1) e += __shfl_xor(e, off);
                if (pxl == 0) sse[wv][kgq * 4 + r] = e;
            }
            if (pxl == 0) {
                int ch = mf * 16 + kgq * 4 + r;
                ssum[wv][ch] = s;
                ssq[wv][ch] = s2;
            }
        }
    }
    __syncthreads();
    if (tid < 144) {
        float s = ssum[0][tid] + ssum[1][tid] + ssum[2][tid] + ssum[3][tid];
        float s2 = ssq[0][tid] + ssq[1][tid] + ssq[2][tid] + ssq[3][tid];
        size_t idx = (((size_t)tid * 16 + b) * 64 + mt) * 2;
        statpart[idx + 0] = s;
        statpart[idx + 1] = s2;
    }
    if (tid >= 144 && tid < 160) {
        int kc = tid - 144;
        float e = sse[0][kc] + sse[1][kc] + sse[2][kc] + sse[3][kc];
        kpart[((size_t)kc * 16 + b) * 64 + mt] = e;
    }
}

// ---------------- K3: finalize — blocks 0..127 BN; 128..383 softmax rinv ----------
__global__ void stats_finalize(const float* __restrict__ statpart,
                               const float* __restrict__ kpart,
                               const float* __restrict__ gq, const float* __restrict__ bq,
                               const float* __restrict__ gv, const float* __restrict__ bv,
                               float* __restrict__ ascale, float* __restrict__ dshift,
                               float* __restrict__ ksm) {
    int tid = threadIdx.x;
    if (blockIdx.x >= 128) {
        int id = blockIdx.x - 128;
        if (tid < 64) {
            float s = kpart[(size_t)id * 64 + tid];
#pragma unroll
            for (int off = 32; off > 0; off >>= 1) s += __shfl_down(s, off);
            if (tid == 0) ksm[id] = 1.0f / s;
        }
        return;
    }
    int sch = blockIdx.x;
    int gch = (sch < 64) ? sch : sch + 16;
    const float* sp = statpart + (size_t)gch * 1024 * 2;
    float s = 0.f, s2 = 0.f;
    for (int i = tid; i < 1024; i += 256) {
        s += sp[i * 2 + 0];
        s2 += sp[i * 2 + 1];
    }
#pragma unroll
    for (int off = 32; off > 0; off >>= 1) {
        s += __shfl_down(s, off);
        s2 += __shfl_down(s2, off);
    }
    __shared__ float red[8];
    int wid = tid >> 6, lane = tid & 63;
    if (lane == 0) { red[wid * 2] = s; red[wid * 2 + 1] = s2; }
    __syncthreads();
    if (tid == 0) {
        float ts = 0.f, ts2 = 0.f;
#pragma unroll
        for (int w2 = 0; w2 < 4; w2++) { ts += red[w2 * 2]; ts2 += red[w2 * 2 + 1]; }
        const float invN = 1.0f / 65536.0f;
        float mean = ts * invN;
        float var = ts2 * invN - mean * mean;
        float g = (sch < 64) ? gq[sch] : gv[sch - 64];
        float be = (sch < 64) ? bq[sch] : bv[sch - 64];
        float a = g * rsqrtf(var + BNEPS);
        ascale[sch] = a;
        dshift[sch] = be - mean * a;
    }
}

// ---------------- K5: merged cl_partial (roles 0..15) + bnq_t (roles 16..79) --------
__global__ void __launch_bounds__(256) cl_bnq(float* __restrict__ qkv,
                                              const float* __restrict__ ksm,
                                              const float* __restrict__ ascale,
                                              const float* __restrict__ dshift,
                                              float* __restrict__ clpart) {
    __shared__ float smem[128 * 65 + 16 * 132 + 16];   // 41.9 KB union
    int role = blockIdx.x, b = blockIdx.y;
    int tid = threadIdx.x;

    if (role >= 16) {
        float (*sv)[65] = (float(*)[65])smem;
        int mt = role - 16;
        int m0 = mt * 64;
        float* qb = qkv + (size_t)b * COUT * MPIX;
        int c = tid & 63, mg = tid >> 6;
        float a = ascale[c], d = dshift[c];
#pragma unroll
        for (int i = 0; i < 16; i++) {
            int m = mg * 16 + i;
            sv[m][c] = fmaf(a, qb[(size_t)(m0 + m) * 64 + c], d);
        }
        __syncthreads();
        int m = tid >> 2, jb = (tid & 3) * 8;
        unsigned dw[8];
#pragma unroll
        for (int j = 0; j < 8; j++) {
            int cc = jb * 2 + 2 * j;
            dw[j] = (unsigned)f2bf(sv[m][cc]) | ((unsigned)f2bf(sv[m][cc + 1]) << 16);
        }
        unsigned* dst = (unsigned*)qb + (size_t)(m0 + m) * 64 + jb;
        *(uint4*)dst = make_uint4(dw[0], dw[1], dw[2], dw[3]);
        *(uint4*)(dst + 4) = make_uint4(dw[4], dw[5], dw[6], dw[7]);
        return;
    }

    float (*vsT)[65] = (float(*)[65])smem;
    float (*pk2)[132] = (float(*)[132])(smem + 128 * 65);
    float* skr = smem + 128 * 65 + 16 * 132;
    int mc = role;
    int m0 = mc * 256;
    int vc = tid & 63, kg = tid >> 6;
    if (tid < 16) skr[tid] = ksm[(size_t)tid * 16 + b];
    float acc[4] = {0.f, 0.f, 0.f, 0.f};
    for (int half = 0; half < 2; half++) {
        int mh = m0 + half * 128;
        __syncthreads();
        for (int i = tid; i < 64 * 128; i += 256) {
            int r = i >> 7, c = i & 127;
            vsT[c][r] = fmaf(ascale[64 + r], qkv[((size_t)b * COUT + 80 + r) * MPIX + mh + c],
                             dshift[64 + r]);
        }
        for (int i = tid; i < 16 * 128; i += 256) {
            int kc = i >> 7, mm = i & 127;
            pk2[kc][mm] = __expf(qkv[((size_t)b * COUT + 64 + kc) * MPIX + mh + mm]) * skr[kc];
        }
        __syncthreads();
        for (int mm = 0; mm < 128; mm++) {
            float vv = vsT[mm][vc];
#pragma unroll
            for (int i = 0; i < 4; i++) {
                int kc = kg * 4 + i;
                acc[i] = fmaf(pk2[kc][mm], vv, acc[i]);
            }
        }
    }
#pragma unroll
    for (int i = 0; i < 4; i++) {
        int kc = kg * 4 + i;
        clpart[(((size_t)b * 16 + mc) * 16 + kc) * 64 + vc] = acc[i];
    }
}

// ---------------- K8: fused MFMA conv + lambda epilogue (q-prefetch ring) ----------
#define SPW 88
#define LD_FRAG(P) __builtin_bit_cast(s16x8, make_int4((P)[0], (P)[2], (P)[4], (P)[6]))
#define STEP(DY, J) do {                                                        \
    const unsigned* pnew_ = xbase + ((DY) + 3) * SPW;                           \
    rw[((J) + 3) & 3][0] = LD_FRAG(pnew_);                                      \
    rw[((J) + 3) & 3][1] = LD_FRAG(pnew_ + 16);                                 \
    int dyn_ = ((DY) + 3 < 22) ? (DY) + 3 : 22;                                 \
    wr[((J) + 3) & 3] = wf[dyn_ * 64 + lane];                                   \
    _Pragma("unroll")                                                           \
    for (int ty_ = 0; ty_ < 4; ty_++) {                                         \
      _Pragma("unroll")                                                         \
      for (int x2_ = 0; x2_ < 2; x2_++) {                                       \
        int t_ = ty_ * 2 + x2_;                                                 \
        acc[t_] = __builtin_amdgcn_mfma_f32_16x16x32_bf16(                      \
            wr[(J) & 3], rw[((J) + ty_) & 3][x2_], acc[t_], 0, 0, 0);           \
      }                                                                         \
    }                                                                           \
  } while (0)

// q-tile address for epilogue tile T (uses y0, xh, h, px, kg from scope)
#define QADDR(T) (&qtb[(size_t)(((h * 32 + y0 + ((T) >> 1)) * 64                \
                                 + (xh * 2 + ((T) & 1)) * 16) + px) * 64 + kg * 8])

__global__ void __launch_bounds__(256, 4) lambda_main(
    const float* __restrict__ qkv, const float* __restrict__ ascale,
    const float* __restrict__ dshift, const float* __restrict__ clpart,
    const short* __restrict__ wfrag, const float* __restrict__ bl,
    float* __restrict__ out) {
    __shared__ unsigned spack[54 * SPW + 8];
    __shared__ float sck[16];

    int vc = blockIdx.x, b = blockIdx.y, h = blockIdx.z;
    int tid = threadIdx.x;

    if (tid < 16) {   // inline cl_reduce: same mc ascending order
        float s = 0.f;
        for (int mc2 = 0; mc2 < 16; mc2++)
            s += clpart[(((size_t)b * 16 + mc2) * 16 + tid) * 64 + vc];
        sck[tid] = s + bl[tid];
    }

    float av = ascale[64 + vc], dv = dshift[64 + vc];
    const float* vrow = qkv + ((size_t)b * COUT + 80 + vc) * MPIX;
    for (int i = tid; i < 54 * SPW; i += 256) {
        int y = i / SPW, e = i - y * SPW;
        int iy = h * 32 + y - PADH;
        float f0 = 0.f, f1 = 0.f;
        if ((unsigned)iy < 64u) {
            int ix0 = e - PADH, ix1 = e - PADH + 1;
            if ((unsigned)ix0 < 64u) f0 = fmaf(av, vrow[iy * 64 + ix0], dv);
            if ((unsigned)ix1 < 64u) f1 = fmaf(av, vrow[iy * 64 + ix1], dv);
        }
        spack[i] = (unsigned)f2bf(f0) | ((unsigned)f2bf(f1) << 16);
    }
    if (tid < 8) spack[54 * SPW + tid] = 0u;
    __syncthreads();

    int lane = tid & 63;
    int wv = tid >> 6;
    int px = lane & 15;
    int kg = lane >> 4;
    const s16x8* wf = (const s16x8*)wfrag;

    const unsigned* qtb = (const unsigned*)(qkv + (size_t)b * COUT * MPIX);
    float* ob = out + (size_t)b * 256 * MPIX;

    float sck_l[4];
#pragma unroll
    for (int r = 0; r < 4; r++) sck_l[r] = sck[kg * 4 + r];
    int kb0 = kg & 1, kb2 = kg & 2;

#pragma unroll 1
    for (int gg = 0; gg < 2; gg++) {
        int y0 = (gg * 4 + wv) * 4;
        const unsigned* base = &spack[y0 * SPW + px + kg * 8];

#pragma unroll 1
        for (int xh = 0; xh < 2; xh++) {
            const unsigned* xbase = base + xh * 32;
            f32x4 acc[8];
#pragma unroll
            for (int t = 0; t < 8; t++) acc[t] = 0.f;

            s16x8 rw[4][2];
            s16x8 wr[4];
#pragma unroll
            for (int r0 = 0; r0 < 3; r0++) {
                const unsigned* p = xbase + r0 * SPW;
                rw[r0][0] = LD_FRAG(p);
                rw[r0][1] = LD_FRAG(p + 16);
            }
#pragma unroll
            for (int s = 0; s < 3; s++) wr[s] = wf[s * 64 + lane];

#pragma unroll 1
            for (int i8 = 0; i8 < 2; i8++) {
                int dyb = i8 * 8;
                STEP(dyb + 0, 0);
                STEP(dyb + 1, 1);
                STEP(dyb + 2, 2);
                STEP(dyb + 3, 3);
                STEP(dyb + 4, 4);
                STEP(dyb + 5, 5);
                STEP(dyb + 6, 6);
                STEP(dyb + 7, 7);
            }
            STEP(16, 0);
            STEP(17, 1);
            STEP(18, 2);
            STEP(19, 3);
            STEP(20, 4);
            STEP(21, 5);
            STEP(22, 6);

            // epilogue with 3-slot q-prefetch ring (2 tiles ahead, static indices)
            uint4 qra[3], qrb[3];
            {
                const unsigned* p0 = QADDR(0);
                qra[0] = *(const uint4*)p0;
                qrb[0] = *(const uint4*)(p0 + 4);
                const unsigned* p1 = QADDR(1);
                qra[1] = *(const uint4*)p1;
                qrb[1] = *(const uint4*)(p1 + 4);
            }
#pragma unroll
            for (int t = 0; t < 8; t++) {
                if (t + 2 < 8) {
                    const unsigned* pn = QADDR(t + 2);
                    qra[(t + 2) % 3] = *(const uint4*)pn;
                    qrb[(t + 2) % 3] = *(const uint4*)(pn + 4);
                }
                int ty = t >> 1, x2 = t & 1;
                int m0 = (h * 32 + y0 + ty) * 64 + (xh * 2 + x2) * 16;
                float lam[4];
#pragma unroll
                for (int r = 0; r < 4; r++) lam[r] = acc[t][r] + sck_l[r];
                uint4 qa = qra[t % 3];
                uint4 qb4 = qrb[t % 3];
                unsigned dws[8] = {qa.x, qa.y, qa.z, qa.w, qb4.x, qb4.y, qb4.z, qb4.w};
                float po[4] = {0.f, 0.f, 0.f, 0.f};
#pragma unroll
                for (int d = 0; d < 8; d++) {
                    float q0 = __builtin_bit_cast(float, dws[d] << 16);
                    float q1 = __builtin_bit_cast(float, dws[d] & 0xffff0000u);
                    int i0 = 2 * d, i1 = 2 * d + 1;
                    po[i0 & 3] = fmaf(q0, lam[i0 >> 2], po[i0 & 3]);
                    po[i1 & 3] = fmaf(q1, lam[i1 >> 2], po[i1 & 3]);
                }
                // 2-step reduce-scatter across kg groups: 3 shfl + 3 add
                float s0 = kb0 ? po[0] : po[1];
                float s1 = kb0 ? po[2] : po[3];
                float r0 = __shfl_xor(s0, 16);
                float r1 = __shfl_xor(s1, 16);
                float alo = (kb0 ? po[1] : po[0]) + r0;
                float bhi = (kb0 ? po[3] : po[2]) + r1;
                float s2 = kb2 ? alo : bhi;
                float r2 = __shfl_xor(s2, 32);
                float fin = (kb2 ? bhi : alo) + r2;
                ob[(size_t)(kg * 64 + vc) * MPIX + m0 + px] = fin;
            }
        }
    }
}

// ---------------- launch ----------------
extern "C" void kernel_launch(void* const* d_in, const int* in_sizes, int n_in,
                              void* d_out, int out_size, void* d_ws, size_t ws_size,
                              hipStream_t stream) {
    const float* x      = (const float*)d_in[0];
    const float* w_qkv  = (const float*)d_in[1];
    const float* gq     = (const float*)d_in[2];
    const float* bq     = (const float*)d_in[3];
    const float* gv     = (const float*)d_in[4];
    const float* bv     = (const float*)d_in[5];
    const float* wl     = (const float*)d_in[6];
    const float* bl     = (const float*)d_in[7];
    float* out = (float*)d_out;

    float* ws     = (float*)d_ws;
    float* qkv    = ws;                    // 9,437,184 floats (q region holds [m][64c])
    float* ascale = qkv + 9437184;         // 128
    float* dshift = ascale + 128;          // 128
    float* clpart = dshift + 128;          // 262,144
    short* wfrag  = (short*)(clpart + 262144);             // 11,776 halfs
    short* wqf    = (short*)(clpart + 262144 + 5888 + 64); // 36,864 halfs
    float* statpart = (float*)(wqf + 36864);               // 294,912 floats
    float* kpart  = statpart + 294912;     // 16,384
    float* ksm    = kpart + 16384;         // 256

    prep_frags<<<190, 256, 0, stream>>>(w_qkv, wl, wqf, wfrag);
    gemm_qkv<<<dim3(64, 16), 256, 0, stream>>>(x, wqf, qkv, statpart, kpart);
    stats_finalize<<<384, 256, 0, stream>>>(statpart, kpart, gq, bq, gv, bv,
                                            ascale, dshift, ksm);
    cl_bnq<<<dim3(80, 16), 256, 0, stream>>>(qkv, ksm, ascale, dshift, clpart);
    lambda_main<<<dim3(64, 16, 2), 256, 0, stream>>>(qkv, ascale, dshift, clpart, wfrag, bl, out);
}

// Round 22
// 189.224 us; speedup vs baseline: 1.0060x; 1.0060x over previous
//
#include <hip/hip_runtime.h>
#include <math.h>

#define NB    16      // batch
#define CDIM  256
#define COUT  144     // 64 q + 16 k + 64 v
#define MPIX  4096    // 64*64
#define SCOPE 23
#define PADH  11
#define BNEPS 1e-5f

typedef __attribute__((ext_vector_type(4))) float f32x4;
typedef __attribute__((ext_vector_type(8))) short s16x8;

__device__ __forceinline__ unsigned short f2bf(float f) {
    unsigned u = __builtin_bit_cast(unsigned, f);
    unsigned r = (u + 0x7FFFu + ((u >> 16) & 1u)) >> 16;
    return (unsigned short)r;
}

// ---------------- K0: both weight-fragment preps merged ----------------
__global__ void prep_frags(const float* __restrict__ w, const float* __restrict__ wl,
                           short* __restrict__ wqf, short* __restrict__ wfrag) {
    int i = blockIdx.x * 256 + threadIdx.x;
    if (i < 36864) {
        int j = i & 7, lane = (i >> 3) & 63;
        int fi = i >> 9;
        int mf = fi % 9, kc = fi / 9;
        int o = mf * 16 + (lane & 15);
        int c = kc * 32 + (lane >> 4) * 8 + j;
        wqf[i] = (short)f2bf(w[o * 256 + c]);
        return;
    }
    int i2 = i - 36864;
    if (i2 < 23 * 64 * 8) {
        int j = i2 & 7, l = (i2 >> 3) & 63, dy = i2 >> 9;
        int k = l & 15, t = ((l >> 4) << 3) + j;
        float wv = (t < SCOPE) ? wl[k * 529 + dy * 23 + t] : 0.f;
        wfrag[i2] = (short)f2bf(wv);
    }
}

// ---------------- K1: qkv GEMM + fused BN stat partials + softmax denominator ----
__global__ void __launch_bounds__(256, 4) gemm_qkv(const float* __restrict__ x,
                                                   const short* __restrict__ wqf,
                                                   float* __restrict__ qkv,
                                                   float* __restrict__ statpart,
                                                   float* __restrict__ kpart) {
    __shared__ unsigned pk[16 * 65];
    __shared__ float ssum[4][144], ssq[4][144];
    __shared__ float sse[4][16];
    int mt = blockIdx.x, b = blockIdx.y;
    int m0 = mt * 64;
    int tid = threadIdx.x;
    int px64 = tid & 63, c2b = tid >> 6;
    int lane = tid & 63, wv = tid >> 6;
    int pxl = lane & 15, kgq = lane >> 4;
    const float* xb = x + (size_t)b * CDIM * MPIX;
    float* qtb = qkv + (size_t)b * COUT * MPIX;
    const s16x8* wfv = (const s16x8*)wqf;

    f32x4 acc[9];
#pragma unroll
    for (int mf = 0; mf < 9; mf++) acc[mf] = 0.f;

#pragma unroll 1
    for (int kc = 0; kc < 8; kc++) {
        if (kc > 0) __syncthreads();
#pragma unroll
        for (int it = 0; it < 4; it++) {
            int c2 = c2b + it * 4;
            float x0 = xb[(size_t)(kc * 32 + 2 * c2) * MPIX + m0 + px64];
            float x1 = xb[(size_t)(kc * 32 + 2 * c2 + 1) * MPIX + m0 + px64];
            pk[c2 * 65 + px64] = (unsigned)f2bf(x0) | ((unsigned)f2bf(x1) << 16);
        }
        __syncthreads();
        const unsigned* bp = &pk[kgq * 4 * 65 + wv * 16 + pxl];
        int4 bi = make_int4(bp[0], bp[65], bp[130], bp[195]);
        s16x8 bf = __builtin_bit_cast(s16x8, bi);
#pragma unroll
        for (int mf = 0; mf < 9; mf++) {
            s16x8 af = wfv[(kc * 9 + mf) * 64 + lane];
            acc[mf] = __builtin_amdgcn_mfma_f32_16x16x32_bf16(af, bf, acc[mf], 0, 0, 0);
        }
    }

    int m = m0 + wv * 16 + pxl;
#pragma unroll
    for (int mf = 0; mf < 9; mf++) {
#pragma unroll
        for (int r = 0; r < 4; r++) {
            int o = mf * 16 + kgq * 4 + r;
            if (mf < 4) qtb[(size_t)m * 64 + o] = acc[mf][r];
            else qkv[((size_t)b * COUT + o) * MPIX + m] = acc[mf][r];
        }
    }

#pragma unroll
    for (int mf = 0; mf < 9; mf++) {
#pragma unroll
        for (int r = 0; r < 4; r++) {
            float s = acc[mf][r];
            float s2 = s * s;
#pragma unroll
            for (int off = 1; off < 16; off <<= 1) {
                s += __shfl_xor(s, off);
                s2 += __shfl_xor(s2, off);
            }
            if (mf == 4) {
                float e = __expf(acc[mf][r]);
#pragma unroll
                for (int off = 1; off < 16; off <<= 1) e += __shfl_xor(e, off);
                if (pxl == 0) sse[wv][kgq * 4 + r] = e;
            }
            if (pxl == 0) {
                int ch = mf * 16 + kgq * 4 + r;
                ssum[wv][ch] = s;
                ssq[wv][ch] = s2;
            }
        }
    }
    __syncthreads();
    if (tid < 144) {
        float s = ssum[0][tid] + ssum[1][tid] + ssum[2][tid] + ssum[3][tid];
        float s2 = ssq[0][tid] + ssq[1][tid] + ssq[2][tid] + ssq[3][tid];
        size_t idx = (((size_t)tid * 16 + b) * 64 + mt) * 2;
        statpart[idx + 0] = s;
        statpart[idx + 1] = s2;
    }
    if (tid >= 144 && tid < 160) {
        int kc = tid - 144;
        float e = sse[0][kc] + sse[1][kc] + sse[2][kc] + sse[3][kc];
        kpart[((size_t)kc * 16 + b) * 64 + mt] = e;
    }
}

// ---------------- K3: finalize — blocks 0..127 BN; 128..383 softmax rinv ----------
__global__ void stats_finalize(const float* __restrict__ statpart,
                               const float* __restrict__ kpart,
                               const float* __restrict__ gq, const float* __restrict__ bq,
                               const float* __restrict__ gv, const float* __restrict__ bv,
                               float* __restrict__ ascale, float* __restrict__ dshift,
                               float* __restrict__ ksm) {
    int tid = threadIdx.x;
    if (blockIdx.x >= 128) {
        int id = blockIdx.x - 128;
        if (tid < 64) {
            float s = kpart[(size_t)id * 64 + tid];
#pragma unroll
            for (int off = 32; off > 0; off >>= 1) s += __shfl_down(s, off);
            if (tid == 0) ksm[id] = 1.0f / s;
        }
        return;
    }
    int sch = blockIdx.x;
    int gch = (sch < 64) ? sch : sch + 16;
    const float* sp = statpart + (size_t)gch * 1024 * 2;
    float s = 0.f, s2 = 0.f;
    for (int i = tid; i < 1024; i += 256) {
        s += sp[i * 2 + 0];
        s2 += sp[i * 2 + 1];
    }
#pragma unroll
    for (int off = 32; off > 0; off >>= 1) {
        s += __shfl_down(s, off);
        s2 += __shfl_down(s2, off);
    }
    __shared__ float red[8];
    int wid = tid >> 6, lane = tid & 63;
    if (lane == 0) { red[wid * 2] = s; red[wid * 2 + 1] = s2; }
    __syncthreads();
    if (tid == 0) {
        float ts = 0.f, ts2 = 0.f;
#pragma unroll
        for (int w2 = 0; w2 < 4; w2++) { ts += red[w2 * 2]; ts2 += red[w2 * 2 + 1]; }
        const float invN = 1.0f / 65536.0f;
        float mean = ts * invN;
        float var = ts2 * invN - mean * mean;
        float g = (sch < 64) ? gq[sch] : gv[sch - 64];
        float be = (sch < 64) ? bq[sch] : bv[sch - 64];
        float a = g * rsqrtf(var + BNEPS);
        ascale[sch] = a;
        dshift[sch] = be - mean * a;
    }
}

// ---------------- K5: merged cl_partial (roles 0..15) + bnq_t (roles 16..79) --------
__global__ void __launch_bounds__(256) cl_bnq(float* __restrict__ qkv,
                                              const float* __restrict__ ksm,
                                              const float* __restrict__ ascale,
                                              const float* __restrict__ dshift,
                                              float* __restrict__ clpart) {
    __shared__ float smem[128 * 65 + 16 * 132 + 16];   // 41.9 KB union
    int role = blockIdx.x, b = blockIdx.y;
    int tid = threadIdx.x;

    if (role >= 16) {
        float (*sv)[65] = (float(*)[65])smem;
        int mt = role - 16;
        int m0 = mt * 64;
        float* qb = qkv + (size_t)b * COUT * MPIX;
        int c = tid & 63, mg = tid >> 6;
        float a = ascale[c], d = dshift[c];
#pragma unroll
        for (int i = 0; i < 16; i++) {
            int m = mg * 16 + i;
            sv[m][c] = fmaf(a, qb[(size_t)(m0 + m) * 64 + c], d);
        }
        __syncthreads();
        int m = tid >> 2, jb = (tid & 3) * 8;
        unsigned dw[8];
#pragma unroll
        for (int j = 0; j < 8; j++) {
            int cc = jb * 2 + 2 * j;
            dw[j] = (unsigned)f2bf(sv[m][cc]) | ((unsigned)f2bf(sv[m][cc + 1]) << 16);
        }
        unsigned* dst = (unsigned*)qb + (size_t)(m0 + m) * 64 + jb;
        *(uint4*)dst = make_uint4(dw[0], dw[1], dw[2], dw[3]);
        *(uint4*)(dst + 4) = make_uint4(dw[4], dw[5], dw[6], dw[7]);
        return;
    }

    float (*vsT)[65] = (float(*)[65])smem;
    float (*pk2)[132] = (float(*)[132])(smem + 128 * 65);
    float* skr = smem + 128 * 65 + 16 * 132;
    int mc = role;
    int m0 = mc * 256;
    int vc = tid & 63, kg = tid >> 6;
    if (tid < 16) skr[tid] = ksm[(size_t)tid * 16 + b];
    float acc[4] = {0.f, 0.f, 0.f, 0.f};
    for (int half = 0; half < 2; half++) {
        int mh = m0 + half * 128;
        __syncthreads();
        for (int i = tid; i < 64 * 128; i += 256) {
            int r = i >> 7, c = i & 127;
            vsT[c][r] = fmaf(ascale[64 + r], qkv[((size_t)b * COUT + 80 + r) * MPIX + mh + c],
                             dshift[64 + r]);
        }
        for (int i = tid; i < 16 * 128; i += 256) {
            int kc = i >> 7, mm = i & 127;
            pk2[kc][mm] = __expf(qkv[((size_t)b * COUT + 64 + kc) * MPIX + mh + mm]) * skr[kc];
        }
        __syncthreads();
        for (int mm = 0; mm < 128; mm++) {
            float vv = vsT[mm][vc];
#pragma unroll
            for (int i = 0; i < 4; i++) {
                int kc = kg * 4 + i;
                acc[i] = fmaf(pk2[kc][mm], vv, acc[i]);
            }
        }
    }
#pragma unroll
    for (int i = 0; i < 4; i++) {
        int kc = kg * 4 + i;
        clpart[(((size_t)b * 16 + mc) * 16 + kc) * 64 + vc] = acc[i];
    }
}

// ---------------- K8: fused MFMA conv + lambda epilogue (R20-best: reduce-scatter) ---
#define SPW 88
#define LD_FRAG(P) __builtin_bit_cast(s16x8, make_int4((P)[0], (P)[2], (P)[4], (P)[6]))
#define STEP(DY, J) do {                                                        \
    const unsigned* pnew_ = xbase + ((DY) + 3) * SPW;                           \
    rw[((J) + 3) & 3][0] = LD_FRAG(pnew_);                                      \
    rw[((J) + 3) & 3][1] = LD_FRAG(pnew_ + 16);                                 \
    int dyn_ = ((DY) + 3 < 22) ? (DY) + 3 : 22;                                 \
    wr[((J) + 3) & 3] = wf[dyn_ * 64 + lane];                                   \
    _Pragma("unroll")                                                           \
    for (int ty_ = 0; ty_ < 4; ty_++) {                                         \
      _Pragma("unroll")                                                         \
      for (int x2_ = 0; x2_ < 2; x2_++) {                                       \
        int t_ = ty_ * 2 + x2_;                                                 \
        acc[t_] = __builtin_amdgcn_mfma_f32_16x16x32_bf16(                      \
            wr[(J) & 3], rw[((J) + ty_) & 3][x2_], acc[t_], 0, 0, 0);           \
      }                                                                         \
    }                                                                           \
  } while (0)

__global__ void __launch_bounds__(256, 4) lambda_main(
    const float* __restrict__ qkv, const float* __restrict__ ascale,
    const float* __restrict__ dshift, const float* __restrict__ clpart,
    const short* __restrict__ wfrag, const float* __restrict__ bl,
    float* __restrict__ out) {
    __shared__ unsigned spack[54 * SPW + 8];
    __shared__ float sck[16];

    int vc = blockIdx.x, b = blockIdx.y, h = blockIdx.z;
    int tid = threadIdx.x;

    if (tid < 16) {   // inline cl_reduce: same mc ascending order
        float s = 0.f;
        for (int mc2 = 0; mc2 < 16; mc2++)
            s += clpart[(((size_t)b * 16 + mc2) * 16 + tid) * 64 + vc];
        sck[tid] = s + bl[tid];
    }

    float av = ascale[64 + vc], dv = dshift[64 + vc];
    const float* vrow = qkv + ((size_t)b * COUT + 80 + vc) * MPIX;
    for (int i = tid; i < 54 * SPW; i += 256) {
        int y = i / SPW, e = i - y * SPW;
        int iy = h * 32 + y - PADH;
        float f0 = 0.f, f1 = 0.f;
        if ((unsigned)iy < 64u) {
            int ix0 = e - PADH, ix1 = e - PADH + 1;
            if ((unsigned)ix0 < 64u) f0 = fmaf(av, vrow[iy * 64 + ix0], dv);
            if ((unsigned)ix1 < 64u) f1 = fmaf(av, vrow[iy * 64 + ix1], dv);
        }
        spack[i] = (unsigned)f2bf(f0) | ((unsigned)f2bf(f1) << 16);
    }
    if (tid < 8) spack[54 * SPW + tid] = 0u;
    __syncthreads();

    int lane = tid & 63;
    int wv = tid >> 6;
    int px = lane & 15;
    int kg = lane >> 4;
    const s16x8* wf = (const s16x8*)wfrag;

    const unsigned* qtb = (const unsigned*)(qkv + (size_t)b * COUT * MPIX);
    float* ob = out + (size_t)b * 256 * MPIX;

    float sck_l[4];
#pragma unroll
    for (int r = 0; r < 4; r++) sck_l[r] = sck[kg * 4 + r];
    int kb0 = kg & 1, kb2 = kg & 2;

#pragma unroll 1
    for (int gg = 0; gg < 2; gg++) {
        int y0 = (gg * 4 + wv) * 4;
        const unsigned* base = &spack[y0 * SPW + px + kg * 8];

#pragma unroll 1
        for (int xh = 0; xh < 2; xh++) {
            const unsigned* xbase = base + xh * 32;
            f32x4 acc[8];
#pragma unroll
            for (int t = 0; t < 8; t++) acc[t] = 0.f;

            s16x8 rw[4][2];
            s16x8 wr[4];
#pragma unroll
            for (int r0 = 0; r0 < 3; r0++) {
                const unsigned* p = xbase + r0 * SPW;
                rw[r0][0] = LD_FRAG(p);
                rw[r0][1] = LD_FRAG(p + 16);
            }
#pragma unroll
            for (int s = 0; s < 3; s++) wr[s] = wf[s * 64 + lane];

#pragma unroll 1
            for (int i8 = 0; i8 < 2; i8++) {
                int dyb = i8 * 8;
                STEP(dyb + 0, 0);
                STEP(dyb + 1, 1);
                STEP(dyb + 2, 2);
                STEP(dyb + 3, 3);
                STEP(dyb + 4, 4);
                STEP(dyb + 5, 5);
                STEP(dyb + 6, 6);
                STEP(dyb + 7, 7);
            }
            STEP(16, 0);
            STEP(17, 1);
            STEP(18, 2);
            STEP(19, 3);
            STEP(20, 4);
            STEP(21, 5);
            STEP(22, 6);

#pragma unroll
            for (int t = 0; t < 8; t++) {
                int ty = t >> 1, x2 = t & 1;
                int m0 = (h * 32 + y0 + ty) * 64 + (xh * 2 + x2) * 16;
                float lam[4];
#pragma unroll
                for (int r = 0; r < 4; r++) lam[r] = acc[t][r] + sck_l[r];
                const unsigned* qp = &qtb[(size_t)(m0 + px) * 64 + kg * 8];
                uint4 qa = *(const uint4*)qp;
                uint4 qb4 = *(const uint4*)(qp + 4);
                unsigned dws[8] = {qa.x, qa.y, qa.z, qa.w, qb4.x, qb4.y, qb4.z, qb4.w};
                float po[4] = {0.f, 0.f, 0.f, 0.f};
#pragma unroll
                for (int d = 0; d < 8; d++) {
                    float q0 = __builtin_bit_cast(float, dws[d] << 16);
                    float q1 = __builtin_bit_cast(float, dws[d] & 0xffff0000u);
                    int i0 = 2 * d, i1 = 2 * d + 1;
                    po[i0 & 3] = fmaf(q0, lam[i0 >> 2], po[i0 & 3]);
                    po[i1 & 3] = fmaf(q1, lam[i1 >> 2], po[i1 & 3]);
                }
                // 2-step reduce-scatter across kg groups: 3 shfl + 3 add
                float s0 = kb0 ? po[0] : po[1];
                float s1 = kb0 ? po[2] : po[3];
                float r0 = __shfl_xor(s0, 16);
                float r1 = __shfl_xor(s1, 16);
                float alo = (kb0 ? po[1] : po[0]) + r0;
                float bhi = (kb0 ? po[3] : po[2]) + r1;
                float s2 = kb2 ? alo : bhi;
                float r2 = __shfl_xor(s2, 32);
                float fin = (kb2 ? bhi : alo) + r2;
                ob[(size_t)(kg * 64 + vc) * MPIX + m0 + px] = fin;
            }
        }
    }
}

// ---------------- launch ----------------
extern "C" void kernel_launch(void* const* d_in, const int* in_sizes, int n_in,
                              void* d_out, int out_size, void* d_ws, size_t ws_size,
                              hipStream_t stream) {
    const float* x      = (const float*)d_in[0];
    const float* w_qkv  = (const float*)d_in[1];
    const float* gq     = (const float*)d_in[2];
    const float* bq     = (const float*)d_in[3];
    const float* gv     = (const float*)d_in[4];
    const float* bv     = (const float*)d_in[5];
    const float* wl     = (const float*)d_in[6];
    const float* bl     = (const float*)d_in[7];
    float* out = (float*)d_out;

    float* ws     = (float*)d_ws;
    float* qkv    = ws;                    // 9,437,184 floats (q region holds [m][64c])
    float* ascale = qkv + 9437184;         // 128
    float* dshift = ascale + 128;          // 128
    float* clpart = dshift + 128;          // 262,144
    short* wfrag  = (short*)(clpart + 262144);             // 11,776 halfs
    short* wqf    = (short*)(clpart + 262144 + 5888 + 64); // 36,864 halfs
    float* statpart = (float*)(wqf + 36864);               // 294,912 floats
    float* kpart  = statpart + 294912;     // 16,384
    float* ksm    = kpart + 16384;         // 256

    prep_frags<<<190, 256, 0, stream>>>(w_qkv, wl, wqf, wfrag);
    gemm_qkv<<<dim3(64, 16), 256, 0, stream>>>(x, wqf, qkv, statpart, kpart);
    stats_finalize<<<384, 256, 0, stream>>>(statpart, kpart, gq, bq, gv, bv,
                                            ascale, dshift, ksm);
    cl_bnq<<<dim3(80, 16), 256, 0, stream>>>(qkv, ksm, ascale, dshift, clpart);
    lambda_main<<<dim3(64, 16, 2), 256, 0, stream>>>(qkv, ascale, dshift, clpart, wfrag, bl, out);
}